// Round 2
// baseline (47.756 us; speedup 1.0000x reference)
//
#include <hip/hip_runtime.h>
#include <stdint.h>

#define DIM_IN  4096
#define DIM_OUT 4096
#define BATCH   64
// words along dim_in: 4096/64 = 64

typedef unsigned long long u64;
typedef uint32_t u32;

// ---------------------------------------------------------------------------
// Input-format detection. The harness may push bool arrays as:
//   bytes  (uint8 0/1)            -> "byte" layout
//   int32  (0/1)                  -> "word" layout
//   float32 (0.0f / 1.0f)         -> "word" layout (bit test via != 0)
// Byte layout: a u32 view has bytes each in {0,1} -> values like 0x00010001;
// P(first 64 words all in {0,1}) = 8^-64, and 0x3F800000 is impossible.
// ---------------------------------------------------------------------------
__device__ __forceinline__ bool is_word_fmt(const u32* __restrict__ p) {
    bool words = true;
#pragma unroll
    for (int i = 0; i < 64; ++i) {
        u32 v = p[i];
        if (v > 1u && v != 0x3F800000u) words = false;
    }
    return words;
}

// ---------------------------------------------------------------------------
// K1: pack masks[i][o] (row-major [4096][4096]) into mp[w][o] (u64),
//     word w of column o holds bits for rows i = w*64 .. w*64+63.
// Grid: (4, 64) x 256 threads. Block = 64 rows x 1024 cols tile.
// Each thread packs 4 adjacent columns (vectorized loads, coalesced writes).
// ---------------------------------------------------------------------------
__global__ __launch_bounds__(256) void pack_masks_kernel(
        const void* __restrict__ masks, u64* __restrict__ mp) {
    const int w    = blockIdx.y;                              // 0..63
    const int o0   = blockIdx.x * 1024 + threadIdx.x * 4;     // 4 columns
    const int row0 = w * 64;
    const bool words = is_word_fmt((const u32*)masks);

    u32 lo[4] = {0u, 0u, 0u, 0u};
    u32 hi[4] = {0u, 0u, 0u, 0u};

    if (words) {
        const u32* pw = (const u32*)masks;
#pragma unroll 8
        for (int r = 0; r < 32; ++r) {
            const uint4 v = *reinterpret_cast<const uint4*>(
                pw + (size_t)(row0 + r) * DIM_OUT + o0);
            lo[0] |= (u32)(v.x != 0u) << r;
            lo[1] |= (u32)(v.y != 0u) << r;
            lo[2] |= (u32)(v.z != 0u) << r;
            lo[3] |= (u32)(v.w != 0u) << r;
        }
#pragma unroll 8
        for (int r = 0; r < 32; ++r) {
            const uint4 v = *reinterpret_cast<const uint4*>(
                pw + (size_t)(row0 + 32 + r) * DIM_OUT + o0);
            hi[0] |= (u32)(v.x != 0u) << r;
            hi[1] |= (u32)(v.y != 0u) << r;
            hi[2] |= (u32)(v.z != 0u) << r;
            hi[3] |= (u32)(v.w != 0u) << r;
        }
    } else {
        // byte layout: one u32 load covers the 4 columns of this thread.
        // Slice trick: s[j] byte c = bits (rows j*8..j*8+7) of column c.
        const u32* pb = (const u32*)masks;
        u32 s[8];
#pragma unroll
        for (int j = 0; j < 8; ++j) {
            u32 sl = 0u;
#pragma unroll
            for (int rr = 0; rr < 8; ++rr) {
                u32 v = pb[((size_t)(row0 + j * 8 + rr) * DIM_OUT + o0) >> 2];
                sl |= (v & 0x01010101u) << rr;   // mask bit0 (robust to 0xFF)
            }
            s[j] = sl;
        }
#pragma unroll
        for (int c = 0; c < 4; ++c) {
            const int sh = 8 * c;
            lo[c] = ((s[0] >> sh) & 0xFFu)
                  | (((s[1] >> sh) & 0xFFu) << 8)
                  | (((s[2] >> sh) & 0xFFu) << 16)
                  | (((s[3] >> sh) & 0xFFu) << 24);
            hi[c] = ((s[4] >> sh) & 0xFFu)
                  | (((s[5] >> sh) & 0xFFu) << 8)
                  | (((s[6] >> sh) & 0xFFu) << 16)
                  | (((s[7] >> sh) & 0xFFu) << 24);
        }
    }

    u64* dst = mp + (size_t)w * DIM_OUT + o0;
#pragma unroll
    for (int c = 0; c < 4; ++c)
        dst[c] = (u64)lo[c] | ((u64)hi[c] << 32);
}

// ---------------------------------------------------------------------------
// K2: pack x[b][i] into xp[b*64 + w] via wave ballot (lane t = bit t).
// Grid: 16 x 256 (64 waves); each wave packs 64 words.
// ---------------------------------------------------------------------------
__global__ __launch_bounds__(256) void pack_x_kernel(
        const void* __restrict__ x, u64* __restrict__ xp) {
    const bool words = is_word_fmt((const u32*)x);
    const int gtid = blockIdx.x * 256 + threadIdx.x;
    const int wave = gtid >> 6;          // 0..63
    const int lane = threadIdx.x & 63;

    for (int k = 0; k < 64; ++k) {
        const int idx = wave * 64 + k;               // 0..4095
        const int b = idx >> 6;
        const int w = idx & 63;
        const size_t e = (size_t)b * DIM_IN + (size_t)w * 64 + lane;
        bool pred;
        if (words) pred = ((const u32*)x)[e] != 0u;
        else       pred = ((const uint8_t*)x)[e] != 0u;
        const u64 m = __ballot(pred);
        if (lane == 0) xp[idx] = m;
    }
}

// ---------------------------------------------------------------------------
// K3: out[b][o] = ((4096 - sum_w popc(xp[b][w] ^ mp[w][o])) > thr[o]) ? 1 : 0
// Output dtype is INT32 (bool output -> int32 path in the harness).
// Grid: (16 o-blocks, 16 b-blocks) x 256 threads; 4 batch rows per thread.
// mp loads coalesced (consecutive o per lane); xp loads are block-uniform
// -> scalar loads.
// ---------------------------------------------------------------------------
__global__ __launch_bounds__(256) void bnn_kernel(
        const u64* __restrict__ mp, const u64* __restrict__ xp,
        const int* __restrict__ thr, int* __restrict__ out) {
    const int o  = blockIdx.x * 256 + threadIdx.x;
    const int b0 = blockIdx.y * 4;

    const u64* __restrict__ x0 = xp + (size_t)(b0 + 0) * 64;
    const u64* __restrict__ x1 = xp + (size_t)(b0 + 1) * 64;
    const u64* __restrict__ x2 = xp + (size_t)(b0 + 2) * 64;
    const u64* __restrict__ x3 = xp + (size_t)(b0 + 3) * 64;

    int a0 = 0, a1 = 0, a2 = 0, a3 = 0;
#pragma unroll 8
    for (int w = 0; w < 64; ++w) {
        const u64 mw = mp[(size_t)w * DIM_OUT + o];
        a0 += __popcll(x0[w] ^ mw);
        a1 += __popcll(x1[w] ^ mw);
        a2 += __popcll(x2[w] ^ mw);
        a3 += __popcll(x3[w] ^ mw);
    }

    const int t = thr[o];
    out[(size_t)(b0 + 0) * DIM_OUT + o] = (DIM_IN - a0) > t ? 1 : 0;
    out[(size_t)(b0 + 1) * DIM_OUT + o] = (DIM_IN - a1) > t ? 1 : 0;
    out[(size_t)(b0 + 2) * DIM_OUT + o] = (DIM_IN - a2) > t ? 1 : 0;
    out[(size_t)(b0 + 3) * DIM_OUT + o] = (DIM_IN - a3) > t ? 1 : 0;
}

// ---------------------------------------------------------------------------
extern "C" void kernel_launch(void* const* d_in, const int* in_sizes, int n_in,
                              void* d_out, int out_size, void* d_ws, size_t ws_size,
                              hipStream_t stream) {
    const void* x     = d_in[0];                 // bool [64][4096]
    const void* masks = d_in[1];                 // bool [4096][4096]
    const int*  thr   = (const int*)d_in[2];     // int32 [4096]
    int* out = (int*)d_out;                      // [64][4096] as int32 0/1

    u64* mp = (u64*)d_ws;                                        // 64*4096*8 = 2 MiB
    u64* xp = (u64*)((char*)d_ws + (size_t)64 * DIM_OUT * 8);    // 4096*8  = 32 KiB

    pack_masks_kernel<<<dim3(4, 64), dim3(256), 0, stream>>>(masks, mp);
    pack_x_kernel<<<dim3(16), dim3(256), 0, stream>>>(x, xp);
    bnn_kernel<<<dim3(16, 16), dim3(256), 0, stream>>>(mp, xp, thr, out);
}

// Round 3
// 40.578 us; speedup vs baseline: 1.1769x; 1.1769x over previous
//
#include <hip/hip_runtime.h>
#include <stdint.h>

#define DIM_IN  4096
#define DIM_OUT 4096
#define BATCH   64
// words along dim_in: 4096/64 = 64

typedef unsigned long long u64;
typedef uint32_t u32;

// ---------------------------------------------------------------------------
// Input-format detection (first 64 u32 words of the array):
//   int32 0/1 or float 0.0/1.0  -> "word" layout (4B per bool)
//   uint8 0/1                   -> "byte" layout (1B per bool)
// Byte layout words look like 0x00010001 (bytes each 0/1); word layout values
// are only {0,1,0x3F800000}. Misclassification prob ~2^-192.
// ---------------------------------------------------------------------------
__device__ __forceinline__ bool is_word_fmt(const u32* __restrict__ p) {
    bool words = true;
#pragma unroll
    for (int i = 0; i < 64; ++i) {
        u32 v = p[i];
        if (v > 1u && v != 0x3F800000u) words = false;
    }
    return words;
}

// ---------------------------------------------------------------------------
// K1 (fused pack):
//  blockIdx.y < 64 : pack masks[i][o] -> mp[w][o] (u64 over rows w*64..w*64+63)
//                    grid.x=4, 256 thr, 4 adjacent columns per thread.
//  blockIdx.y >= 64: pack x[b][i] -> xp[b*64+w] via wave ballot.
//                    16 block-slots * 4 waves = 64 waves, 64 words each.
// ---------------------------------------------------------------------------
__global__ __launch_bounds__(256) void pack_kernel(
        const void* __restrict__ masks, const void* __restrict__ x,
        u64* __restrict__ mp, u64* __restrict__ xp) {
    if (blockIdx.y < 64) {
        const int w    = blockIdx.y;                              // 0..63
        const int o0   = blockIdx.x * 1024 + threadIdx.x * 4;     // 4 columns
        const int row0 = w * 64;
        const bool words = is_word_fmt((const u32*)masks);

        u32 lo[4] = {0u, 0u, 0u, 0u};
        u32 hi[4] = {0u, 0u, 0u, 0u};

        if (words) {
            const u32* pw = (const u32*)masks;
#pragma unroll 8
            for (int r = 0; r < 32; ++r) {
                const uint4 v = *reinterpret_cast<const uint4*>(
                    pw + (size_t)(row0 + r) * DIM_OUT + o0);
                lo[0] |= (u32)(v.x != 0u) << r;
                lo[1] |= (u32)(v.y != 0u) << r;
                lo[2] |= (u32)(v.z != 0u) << r;
                lo[3] |= (u32)(v.w != 0u) << r;
            }
#pragma unroll 8
            for (int r = 0; r < 32; ++r) {
                const uint4 v = *reinterpret_cast<const uint4*>(
                    pw + (size_t)(row0 + 32 + r) * DIM_OUT + o0);
                hi[0] |= (u32)(v.x != 0u) << r;
                hi[1] |= (u32)(v.y != 0u) << r;
                hi[2] |= (u32)(v.z != 0u) << r;
                hi[3] |= (u32)(v.w != 0u) << r;
            }
        } else {
            // byte layout: one u32 load covers this thread's 4 columns.
            // s[j] byte c = bits (rows j*8..j*8+7) of column c.
            const u32* pb = (const u32*)masks;
            u32 s[8];
#pragma unroll
            for (int j = 0; j < 8; ++j) {
                u32 sl = 0u;
#pragma unroll
                for (int rr = 0; rr < 8; ++rr) {
                    u32 v = pb[((size_t)(row0 + j * 8 + rr) * DIM_OUT + o0) >> 2];
                    sl |= (v & 0x01010101u) << rr;
                }
                s[j] = sl;
            }
#pragma unroll
            for (int c = 0; c < 4; ++c) {
                const int sh = 8 * c;
                lo[c] = ((s[0] >> sh) & 0xFFu)
                      | (((s[1] >> sh) & 0xFFu) << 8)
                      | (((s[2] >> sh) & 0xFFu) << 16)
                      | (((s[3] >> sh) & 0xFFu) << 24);
                hi[c] = ((s[4] >> sh) & 0xFFu)
                      | (((s[5] >> sh) & 0xFFu) << 8)
                      | (((s[6] >> sh) & 0xFFu) << 16)
                      | (((s[7] >> sh) & 0xFFu) << 24);
            }
        }

        u64* dst = mp + (size_t)w * DIM_OUT + o0;
#pragma unroll
        for (int c = 0; c < 4; ++c)
            dst[c] = (u64)lo[c] | ((u64)hi[c] << 32);
    } else {
        // ------------------- x pack -------------------
        const bool words = is_word_fmt((const u32*)x);
        const int bxid = (blockIdx.y - 64) * 4 + blockIdx.x;  // 0..15
        const int wave = bxid * 4 + (threadIdx.x >> 6);       // 0..63
        const int lane = threadIdx.x & 63;
        const int base = wave * 64;                           // word index base

#pragma unroll 16
        for (int k = 0; k < 64; ++k) {
            const int idx = base + k;                         // 0..4095
            const size_t e = (size_t)idx * 64 + lane;         // element index
            bool pred;
            if (words) pred = ((const u32*)x)[e] != 0u;
            else       pred = ((const uint8_t*)x)[e] != 0u;
            const u64 m = __ballot(pred);
            if (lane == 0) xp[idx] = m;
        }
    }
}

// ---------------------------------------------------------------------------
// K2: out[b][o] = ((4096 - sum_w popc(xp[b][w] ^ mp[w][o])) > thr[o]) ? 1 : 0
// Output dtype INT32 (bool output -> int32 harness path).
// Grid: (16 o-blocks, 16 b-blocks) x 256 threads; 4 batch rows per thread.
// ---------------------------------------------------------------------------
__global__ __launch_bounds__(256) void bnn_kernel(
        const u64* __restrict__ mp, const u64* __restrict__ xp,
        const int* __restrict__ thr, int* __restrict__ out) {
    const int o  = blockIdx.x * 256 + threadIdx.x;
    const int b0 = blockIdx.y * 4;

    const u64* __restrict__ x0 = xp + (size_t)(b0 + 0) * 64;
    const u64* __restrict__ x1 = xp + (size_t)(b0 + 1) * 64;
    const u64* __restrict__ x2 = xp + (size_t)(b0 + 2) * 64;
    const u64* __restrict__ x3 = xp + (size_t)(b0 + 3) * 64;

    int a0 = 0, a1 = 0, a2 = 0, a3 = 0;
#pragma unroll 16
    for (int w = 0; w < 64; ++w) {
        const u64 mw = mp[(size_t)w * DIM_OUT + o];
        a0 += __popcll(x0[w] ^ mw);
        a1 += __popcll(x1[w] ^ mw);
        a2 += __popcll(x2[w] ^ mw);
        a3 += __popcll(x3[w] ^ mw);
    }

    const int t = thr[o];
    out[(size_t)(b0 + 0) * DIM_OUT + o] = (DIM_IN - a0) > t ? 1 : 0;
    out[(size_t)(b0 + 1) * DIM_OUT + o] = (DIM_IN - a1) > t ? 1 : 0;
    out[(size_t)(b0 + 2) * DIM_OUT + o] = (DIM_IN - a2) > t ? 1 : 0;
    out[(size_t)(b0 + 3) * DIM_OUT + o] = (DIM_IN - a3) > t ? 1 : 0;
}

// ---------------------------------------------------------------------------
extern "C" void kernel_launch(void* const* d_in, const int* in_sizes, int n_in,
                              void* d_out, int out_size, void* d_ws, size_t ws_size,
                              hipStream_t stream) {
    const void* x     = d_in[0];                 // bool [64][4096]
    const void* masks = d_in[1];                 // bool [4096][4096]
    const int*  thr   = (const int*)d_in[2];     // int32 [4096]
    int* out = (int*)d_out;                      // [64][4096] int32 0/1

    u64* mp = (u64*)d_ws;                                        // 2 MiB
    u64* xp = (u64*)((char*)d_ws + (size_t)64 * DIM_OUT * 8);    // 32 KiB

    // y 0..63: mask packing; y 64..67: x packing (16 block-slots).
    pack_kernel<<<dim3(4, 68), dim3(256), 0, stream>>>(masks, x, mp, xp);
    bnn_kernel<<<dim3(16, 16), dim3(256), 0, stream>>>(mp, xp, thr, out);
}